// Round 17
// baseline (377.480 us; speedup 1.0000x reference)
//
#include <hip/hip_runtime.h>
#include <hip/hip_fp16.h>
#include <math.h>

#define N_NODESC 100000
#define N_EDGESC 1600000
#define NBUCK 1563        // ceil(100000 / 64) -- 64 nodes per bucket (both sorts)
#define BSLACK 1280       // slots per bucket region (mean 1024 + 8 sigma)
#define SCHUNK 4096       // edges per scatter block -> 391 blocks
#define NSBLK 391         // ceil(1.6M / 4096)

// fast tanh via native exp: tanh(x) = sign(x) * (1 - e) / (1 + e), e = exp(-2|x|)
__device__ __forceinline__ float fast_tanh(float x) {
    float ax = fabsf(x);
    float e = __expf(-2.f * ax);
    float r = (1.f - e) * __builtin_amdgcn_rcpf(1.f + e);
    return copysignf(r, x);
}

__global__ void binit_kernel(int* __restrict__ bcur, int* __restrict__ sbcur) {
    int i = blockIdx.x * blockDim.x + threadIdx.x;
    if (i < NBUCK) { bcur[i] = i * BSLACK; sbcur[i] = i * BSLACK; }
}

// ---------------- dual counting sort: dst-sort (edges) + src-sort (1-byte ids) ----------------
__global__ __launch_bounds__(1024) void scatter_dual_kernel(
    const int* __restrict__ src, const int* __restrict__ dst,
    int* __restrict__ bcur, int* __restrict__ sbcur,
    unsigned* __restrict__ bedges, unsigned char* __restrict__ sbytes) {
    __shared__ int histd[NBUCK];
    __shared__ int hists[NBUCK];
    int tid = threadIdx.x;
    int e_beg = blockIdx.x * SCHUNK;
    int e_end = min(e_beg + SCHUNK, N_EDGESC);
    for (int i = tid; i < NBUCK; i += 1024) { histd[i] = 0; hists[i] = 0; }
    __syncthreads();

    int ss[4], dd[4];
    int cnt = 0;
    for (int i = e_beg + tid; i < e_end; i += 1024) {
        ss[cnt] = src[i];
        dd[cnt] = dst[i];
        cnt++;
    }
#pragma unroll
    for (int j = 0; j < 4; j++) {
        if (j < cnt) {
            atomicAdd(&histd[dd[j] >> 6], 1);
            atomicAdd(&hists[ss[j] >> 6], 1);
        }
    }
    __syncthreads();
    for (int i = tid; i < NBUCK; i += 1024) {
        int c = histd[i];
        if (c > 0) histd[i] = atomicAdd(&bcur[i], c);
        int c2 = hists[i];
        if (c2 > 0) hists[i] = atomicAdd(&sbcur[i], c2);
    }
    __syncthreads();
#pragma unroll
    for (int j = 0; j < 4; j++) {
        if (j < cnt) {
            int slot = atomicAdd(&histd[dd[j] >> 6], 1);
            bedges[slot] = (unsigned)ss[j] | ((unsigned)(dd[j] & 63) << 17);
            int slot2 = atomicAdd(&hists[ss[j] >> 6], 1);
            sbytes[slot2] = (unsigned char)(ss[j] & 63);
        }
    }
}

// ---------------- fused fc1 (tanh) + filt GEMM; deg rebuilt from src-sort ----------------
// xs stored fp16 (r10 epilogue, proven correct: absmax 0.015625 passed).
__global__ __launch_bounds__(256) void gemm_kernel(
    const float* __restrict__ feat,
    const float* __restrict__ w1, const float* __restrict__ b1,
    const float* __restrict__ w2, const float* __restrict__ b2,
    const int* __restrict__ sbcur, const unsigned char* __restrict__ sbytes,
    float* __restrict__ h1, __half* __restrict__ xs) {
    __shared__ float sf[128 * 68];
    __shared__ int ldeg[128];
    int tid = threadIdx.x;
    int base = blockIdx.x * 128;
    if (tid < 128) ldeg[tid] = 0;
    for (int k = 0; k < 8; k++) {
        int fi = tid + k * 256;
        int node = fi >> 4, f4 = fi & 15;
        float4 v = make_float4(0.f, 0.f, 0.f, 0.f);
        if (base + node < N_NODESC)
            v = ((const float4*)feat)[(size_t)(base + node) * 16 + f4];
        float* d = &sf[node * 68 + f4 * 4];
        d[0] = v.x; d[1] = v.y; d[2] = v.z; d[3] = v.w;
    }
    __syncthreads();

    // out-degree count for this block's 128 nodes (2 src-buckets)
#pragma unroll
    for (int h = 0; h < 2; h++) {
        int sb = blockIdx.x * 2 + h;
        if (sb < NBUCK) {
            int sbeg = sb * BSLACK;
            int sm = sbcur[sb] - sbeg;
            for (int i = tid; i < sm; i += 256)
                atomicAdd(&ldeg[h * 64 + (int)sbytes[sbeg + i]], 1);
        }
    }

    int lane = tid & 63;
    int og = __builtin_amdgcn_readfirstlane(tid >> 6);
    const float* wp1 = w1 + og * 16 * 64;
    const float* wp2 = w2 + og * 16 * 64;

    float a1[2][16], a2[2][16];
#pragma unroll
    for (int o = 0; o < 16; o++) {
        float bb1 = b1[og * 16 + o], bb2 = b2[og * 16 + o];
        a1[0][o] = bb1; a1[1][o] = bb1;
        a2[0][o] = bb2; a2[1][o] = bb2;
    }

    for (int fq = 0; fq < 16; fq++) {
        float4 fv0 = *(const float4*)&sf[lane * 68 + fq * 4];
        float4 fv1 = *(const float4*)&sf[(lane + 64) * 68 + fq * 4];
#pragma unroll
        for (int o = 0; o < 16; o++) {
            float4 wv1 = *(const float4*)&wp1[o * 64 + fq * 4];
            float4 wv2 = *(const float4*)&wp2[o * 64 + fq * 4];
            a1[0][o] += fv0.x * wv1.x + fv0.y * wv1.y + fv0.z * wv1.z + fv0.w * wv1.w;
            a1[1][o] += fv1.x * wv1.x + fv1.y * wv1.y + fv1.z * wv1.z + fv1.w * wv1.w;
            a2[0][o] += fv0.x * wv2.x + fv0.y * wv2.y + fv0.z * wv2.z + fv0.w * wv2.w;
            a2[1][o] += fv1.x * wv2.x + fv1.y * wv2.y + fv1.z * wv2.z + fv1.w * wv2.w;
        }
    }

    __syncthreads();   // ldeg complete before epilogue reads it

#pragma unroll
    for (int j = 0; j < 2; j++) {
        int g = base + lane + j * 64;
        if (g >= N_NODESC) continue;
        float is = rsqrtf(fmaxf((float)ldeg[j * 64 + lane], 1.f));
#pragma unroll
        for (int oq = 0; oq < 4; oq++) {
            float4 t;
            t.x = fast_tanh(a1[j][oq * 4 + 0]); t.y = fast_tanh(a1[j][oq * 4 + 1]);
            t.z = fast_tanh(a1[j][oq * 4 + 2]); t.w = fast_tanh(a1[j][oq * 4 + 3]);
            ((float4*)h1)[(size_t)g * 16 + og * 4 + oq] = t;
            ushort4 us;
            us.x = __half_as_ushort(__float2half_rn(a2[j][oq * 4 + 0] * is));
            us.y = __half_as_ushort(__float2half_rn(a2[j][oq * 4 + 1] * is));
            us.z = __half_as_ushort(__float2half_rn(a2[j][oq * 4 + 2] * is));
            us.w = __half_as_ushort(__float2half_rn(a2[j][oq * 4 + 3] * is));
            ((ushort4*)xs)[(size_t)g * 16 + og * 4 + oq] = us;
        }
    }
}

// ---------------- per-bucket aggregation: fp16 dword-paired gather ----------------
// Constraint set from r10/r11/r14: (a) loads must be >=dword (sub-dword fp16
// was 1.75x slower); (b) addressing must stay single-scalar-base (lane-varying
// shuffle idx -> flat loads was 1.85x slower); (c) fp32 form is delivered-
// bytes-bound (MLP doubling neutral). This satisfies all three: fp16 rows
// (128B), one global_load_dword covers TWO edges -- lanes 0-31 = edge A's 64
// features as __half2, lanes 32-63 = edge B via VGPR offset hi*(sjB-sjA)*128
// added to A's scalar base. Shuffle idx uniform (2j / 2j+1 -> readlane).
// Halves both bytes (410->205 MB) and load instructions vs fp32.
__global__ __launch_bounds__(256) void agg5_kernel(const int* __restrict__ bcur,
                                                   const unsigned* __restrict__ bedges,
                                                   const __half* __restrict__ xs,
                                                   float* __restrict__ h2) {
    __shared__ unsigned eraw[BSLACK];
    __shared__ unsigned eled[BSLACK];
    __shared__ int loff[65];
    __shared__ int lcnt[64];
    __shared__ int lcur[64];
    int tid = threadIdx.x, lane = tid & 63, wid = tid >> 6;
    int b = blockIdx.x;
    int beg = b * BSLACK;
    int m = bcur[b] - beg;             // edges in this bucket

    if (tid < 64) lcnt[tid] = 0;
    __syncthreads();
    for (int i = tid; i < m; i += 256) {
        unsigned pk = bedges[beg + i];
        eraw[i] = pk;
        atomicAdd(&lcnt[pk >> 17], 1);
    }
    __syncthreads();
    if (wid == 0) {                    // 64-entry exclusive scan in wave 0
        int c = lcnt[lane];
        int v = c;
#pragma unroll
        for (int off = 1; off < 64; off <<= 1) {
            int t = __shfl_up(v, off, 64);
            if (lane >= off) v += t;
        }
        loff[lane] = v - c;
        lcur[lane] = v - c;
        if (lane == 63) loff[64] = v;  // == m
    }
    __syncthreads();
    for (int i = tid; i < m; i += 256) {
        unsigned pk = eraw[i];
        int pos = atomicAdd(&lcur[pk >> 17], 1);
        eled[pos] = pk & 0x1FFFFu;
    }
    __syncthreads();

    int nbase = b * 64;
    int lo = lane & 31;                // feature-pair index
    int hi = lane >> 5;                // edge-of-pair selector
    int voffb = lo * 4;                // byte offset of __half2 within a row
#pragma unroll 1
    for (int t = 0; t < 16; t++) {
        int nl = wid * 16 + t;
        int s0 = loff[nl], s1 = loff[nl + 1];
        float ax = 0.f, ay = 0.f;
        for (int k = s0; k < s1; k += 32) {
            int cnt = s1 - k; if (cnt > 32) cnt = 32;   // wave-uniform
            int npair = (cnt + 1) >> 1;                 // wave-uniform
            unsigned sv = eled[min(k + lo, s1 - 1)];    // 32 edge ids (dup in hi half)
            float vx[16], vy[16];
#pragma unroll
            for (int j = 0; j < 16; j++) {
                if (j < npair) {
                    int sjA = __shfl((int)sv, 2 * j, 64);      // uniform -> SGPR
                    int sjB = __shfl((int)sv, 2 * j + 1, 64);  // uniform -> SGPR
                    const char* basep = (const char*)(xs + (size_t)sjA * 64);
                    int rowd = (sjB - sjA) * 128;              // scalar
                    int off = voffb + (hi ? rowd : 0);         // VGPR voffset
                    __half2 hv = *(const __half2*)(basep + off);
                    float2 f = __half22float2(hv);
                    // zero edge-B contribution on odd tail (idxB >= s1)
                    float msk = (hi && (k + 2 * j + 1 >= s1)) ? 0.f : 1.f;
                    vx[j] = f.x * msk; vy[j] = f.y * msk;
                }
            }
#pragma unroll
            for (int j = 0; j < 16; j++)
                if (j < npair) { ax += vx[j]; ay += vy[j]; }
        }
        // fold edge-A (lanes 0-31) and edge-B (lanes 32-63) partials
        ax += __shfl_xor(ax, 32, 64);
        ay += __shfl_xor(ay, 32, 64);
        int g = nbase + nl;
        if (g < N_NODESC && lane < 32) {
            float isq = rsqrtf(fmaxf((float)(s1 - s0), 1.f));
            float2 o = make_float2(ax * isq, ay * isq);
            *(float2*)&h2[(size_t)g * 64 + lo * 2] = o;
        }
    }
}

// ---------------- channel-attention scores, gemm-style operand pattern (r16-proven) ----------------
__global__ __launch_bounds__(256) void att3_kernel(const float* __restrict__ h1,
                                                   const float* __restrict__ h2,
                                                   const float* __restrict__ aw1,
                                                   const float* __restrict__ ab1,
                                                   const float* __restrict__ aw2,
                                                   float* __restrict__ wsum) {
    __shared__ float sf[2][64 * 68];
    __shared__ float ssc[2][2][64];    // [branch][cgroup][node]
    int tid = threadIdx.x, lane = tid & 63;
    int wid = __builtin_amdgcn_readfirstlane(tid >> 6);
    int br = wid >> 1, cg = wid & 1;   // wave-uniform scalars
    int base = blockIdx.x * 64;

    // stage both branches: 4 f4/thread/branch, all 8 issued before barrier
#pragma unroll
    for (int b = 0; b < 2; b++) {
        const float* H = b ? h2 : h1;
#pragma unroll
        for (int k = 0; k < 4; k++) {
            int fi = tid + k * 256;
            int node = fi >> 4, f4 = fi & 15;
            float4 v = make_float4(0.f, 0.f, 0.f, 0.f);
            if (base + node < N_NODESC)
                v = ((const float4*)H)[(size_t)(base + node) * 16 + f4];
            float* d = &sf[b][node * 68 + f4 * 4];
            d[0] = v.x; d[1] = v.y; d[2] = v.z; d[3] = v.w;
        }
    }
    __syncthreads();

    // wave (br,cg): lane <-> node, channels cg*16..cg*16+15
    float acc[16];
#pragma unroll
    for (int c = 0; c < 16; c++) acc[c] = ab1[cg * 16 + c];
    const float* sfb = &sf[br][lane * 68];
    for (int fq = 0; fq < 16; fq++) {
        float4 hv = *(const float4*)&sfb[fq * 4];
#pragma unroll
        for (int k = 0; k < 4; k++) {
            float h = (k == 0) ? hv.x : (k == 1) ? hv.y : (k == 2) ? hv.z : hv.w;
            const float* wp = &aw1[(fq * 4 + k) * 32 + cg * 16];  // uniform addr
#pragma unroll
            for (int cq = 0; cq < 4; cq++) {
                float4 wv = *(const float4*)&wp[cq * 4];
                acc[cq * 4 + 0] += h * wv.x; acc[cq * 4 + 1] += h * wv.y;
                acc[cq * 4 + 2] += h * wv.z; acc[cq * 4 + 3] += h * wv.w;
            }
        }
    }
    float s = 0.f;
#pragma unroll
    for (int c = 0; c < 16; c++) s += fast_tanh(acc[c]) * aw2[cg * 16 + c];
    ssc[br][cg][lane] = s;
    __syncthreads();

    // reduce: threads 0..127 cover [branch][node]; branch uniform per wave
    if (tid < 128) {
        int b2 = tid >> 6, node = tid & 63;
        float v = ssc[b2][0][node] + ssc[b2][1][node];
        if (base + node >= N_NODESC) v = 0.f;
#pragma unroll
        for (int off = 32; off; off >>= 1) v += __shfl_down(v, off, 64);
        if (node == 0) atomicAdd(&wsum[b2], v);
    }
}

// ---------------- fused beta + combine + fc2 ----------------
__global__ __launch_bounds__(256) void out_kernel(const float* __restrict__ h1,
                                                  const float* __restrict__ h2,
                                                  const float* __restrict__ wsum,
                                                  const float* __restrict__ w,
                                                  const float* __restrict__ b,
                                                  float* __restrict__ out) {
    __shared__ float sw[16 * 68];
    int tid = threadIdx.x;
    {
        int o = tid >> 4, f4 = tid & 15;
        float4 v = ((const float4*)w)[tid];
        float* d = &sw[o * 68 + f4 * 4];
        d[0] = v.x; d[1] = v.y; d[2] = v.z; d[3] = v.w;
    }
    __syncthreads();
    float w0 = wsum[0] * (1.f / (float)N_NODESC);
    float w1 = wsum[1] * (1.f / (float)N_NODESC);
    float mx = fmaxf(w0, w1);
    float e0 = __expf(w0 - mx), e1 = __expf(w1 - mx);
    float inv = 1.f / (e0 + e1);
    float b0 = e0 * inv, b1v = e1 * inv;

    int o = tid & 15, ln = tid >> 4;
    int node = blockIdx.x * 16 + ln;
    if (node >= N_NODESC) return;
    const float4* r1 = (const float4*)(h1 + (size_t)node * 64);
    const float4* r2 = (const float4*)(h2 + (size_t)node * 64);
    float acc = b[o];
    for (int fq = 0; fq < 16; fq++) {
        float4 x1 = r1[fq], x2 = r2[fq];
        float4 wv = *(const float4*)&sw[o * 68 + fq * 4];
        acc += (b0 * x1.x + b1v * x2.x) * wv.x + (b0 * x1.y + b1v * x2.y) * wv.y
             + (b0 * x1.z + b1v * x2.z) * wv.z + (b0 * x1.w + b1v * x2.w) * wv.w;
    }
    out[(size_t)node * 16 + o] = acc;
}

extern "C" void kernel_launch(void* const* d_in, const int* in_sizes, int n_in,
                              void* d_out, int out_size, void* d_ws, size_t ws_size,
                              hipStream_t stream) {
    (void)in_sizes; (void)n_in; (void)out_size; (void)ws_size;
    const float* feat = (const float*)d_in[0];
    const int*   esrc = (const int*)d_in[1];
    const int*   edst = (const int*)d_in[2];
    const float* fc1w = (const float*)d_in[3];
    const float* fc1b = (const float*)d_in[4];
    const float* fltw = (const float*)d_in[5];
    const float* fltb = (const float*)d_in[6];
    const float* aw1  = (const float*)d_in[7];
    const float* ab1  = (const float*)d_in[8];
    const float* aw2  = (const float*)d_in[9];
    const float* fc2w = (const float*)d_in[10];
    const float* fc2b = (const float*)d_in[11];
    float* out = (float*)d_out;

    char* ws = (char*)d_ws;
    size_t off = 0;
    auto alloc = [&](size_t bytes) {
        char* p = ws + off;
        off += (bytes + 255) & ~(size_t)255;
        return p;
    };
    float*         h1     = (float*)alloc((size_t)N_NODESC * 64 * 4);
    __half*        xs     = (__half*)alloc((size_t)N_NODESC * 64 * 2);
    float*         h2     = (float*)alloc((size_t)N_NODESC * 64 * 4);
    int*           bcur   = (int*)alloc((size_t)NBUCK * 4);
    int*           sbcur  = (int*)alloc((size_t)NBUCK * 4);
    unsigned*      bedges = (unsigned*)alloc((size_t)NBUCK * BSLACK * 4);  // 8 MB
    unsigned char* sbytes = (unsigned char*)alloc((size_t)NBUCK * BSLACK); // 2 MB
    float*         wsum   = (float*)alloc(16 * 4);

    hipMemsetAsync(wsum, 0, 2 * 4, stream);

    binit_kernel<<<(NBUCK + 255) / 256, 256, 0, stream>>>(bcur, sbcur);
    scatter_dual_kernel<<<NSBLK, 1024, 0, stream>>>(esrc, edst, bcur, sbcur,
                                                    bedges, sbytes);
    gemm_kernel<<<(N_NODESC + 127) / 128, 256, 0, stream>>>(
        feat, fc1w, fc1b, fltw, fltb, sbcur, sbytes, h1, xs);
    agg5_kernel<<<NBUCK, 256, 0, stream>>>(bcur, bedges, xs, h2);
    att3_kernel<<<NBUCK, 256, 0, stream>>>(h1, h2, aw1, ab1, aw2, wsum);
    out_kernel<<<(N_NODESC + 15) / 16, 256, 0, stream>>>(h1, h2, wsum,
                                                         fc2w, fc2b, out);
}

// Round 18
// 298.319 us; speedup vs baseline: 1.2654x; 1.2654x over previous
//
#include <hip/hip_runtime.h>
#include <math.h>

#define N_NODESC 100000
#define N_EDGESC 1600000
#define NBUCK 1563        // ceil(100000 / 64) -- 64 nodes per bucket (both sorts)
#define BSLACK 1280       // slots per bucket region (mean 1024 + 8 sigma)
#define SCHUNK 4096       // edges per scatter block -> 391 blocks
#define NSBLK 391         // ceil(1.6M / 4096)
#define NSLOT 32          // wsum accumulation slots per branch (atomic spread)

// fast tanh via native exp: tanh(x) = sign(x) * (1 - e) / (1 + e), e = exp(-2|x|)
__device__ __forceinline__ float fast_tanh(float x) {
    float ax = fabsf(x);
    float e = __expf(-2.f * ax);
    float r = (1.f - e) * __builtin_amdgcn_rcpf(1.f + e);
    return copysignf(r, x);
}

__global__ void binit_kernel(int* __restrict__ bcur, int* __restrict__ sbcur) {
    int i = blockIdx.x * blockDim.x + threadIdx.x;
    if (i < NBUCK) { bcur[i] = i * BSLACK; sbcur[i] = i * BSLACK; }
}

// ---------------- dual counting sort: dst-sort (edges) + src-sort (1-byte ids) ----------------
__global__ __launch_bounds__(1024) void scatter_dual_kernel(
    const int* __restrict__ src, const int* __restrict__ dst,
    int* __restrict__ bcur, int* __restrict__ sbcur,
    unsigned* __restrict__ bedges, unsigned char* __restrict__ sbytes) {
    __shared__ int histd[NBUCK];
    __shared__ int hists[NBUCK];
    int tid = threadIdx.x;
    int e_beg = blockIdx.x * SCHUNK;
    int e_end = min(e_beg + SCHUNK, N_EDGESC);
    for (int i = tid; i < NBUCK; i += 1024) { histd[i] = 0; hists[i] = 0; }
    __syncthreads();

    int ss[4], dd[4];
    int cnt = 0;
    for (int i = e_beg + tid; i < e_end; i += 1024) {
        ss[cnt] = src[i];
        dd[cnt] = dst[i];
        cnt++;
    }
#pragma unroll
    for (int j = 0; j < 4; j++) {
        if (j < cnt) {
            atomicAdd(&histd[dd[j] >> 6], 1);
            atomicAdd(&hists[ss[j] >> 6], 1);
        }
    }
    __syncthreads();
    for (int i = tid; i < NBUCK; i += 1024) {
        int c = histd[i];
        if (c > 0) histd[i] = atomicAdd(&bcur[i], c);
        int c2 = hists[i];
        if (c2 > 0) hists[i] = atomicAdd(&sbcur[i], c2);
    }
    __syncthreads();
#pragma unroll
    for (int j = 0; j < 4; j++) {
        if (j < cnt) {
            int slot = atomicAdd(&histd[dd[j] >> 6], 1);
            bedges[slot] = (unsigned)ss[j] | ((unsigned)(dd[j] & 63) << 17);
            int slot2 = atomicAdd(&hists[ss[j] >> 6], 1);
            sbytes[slot2] = (unsigned char)(ss[j] & 63);
        }
    }
}

// ---------------- fused fc1 (tanh) + filt GEMM; deg rebuilt from src-sort ----------------
// xs fp32 (fp16 gather refuted three ways: r10 sub-dword, r11 bpermute,
// r17 conditional-voffset -- all ~115-120us vs 64.5us fp32).
__global__ __launch_bounds__(256) void gemm_kernel(
    const float* __restrict__ feat,
    const float* __restrict__ w1, const float* __restrict__ b1,
    const float* __restrict__ w2, const float* __restrict__ b2,
    const int* __restrict__ sbcur, const unsigned char* __restrict__ sbytes,
    float* __restrict__ h1, float* __restrict__ xs) {
    __shared__ float sf[128 * 68];
    __shared__ int ldeg[128];
    int tid = threadIdx.x;
    int base = blockIdx.x * 128;
    if (tid < 128) ldeg[tid] = 0;
    for (int k = 0; k < 8; k++) {
        int fi = tid + k * 256;
        int node = fi >> 4, f4 = fi & 15;
        float4 v = make_float4(0.f, 0.f, 0.f, 0.f);
        if (base + node < N_NODESC)
            v = ((const float4*)feat)[(size_t)(base + node) * 16 + f4];
        float* d = &sf[node * 68 + f4 * 4];
        d[0] = v.x; d[1] = v.y; d[2] = v.z; d[3] = v.w;
    }
    __syncthreads();

    // out-degree count for this block's 128 nodes (2 src-buckets)
#pragma unroll
    for (int h = 0; h < 2; h++) {
        int sb = blockIdx.x * 2 + h;
        if (sb < NBUCK) {
            int sbeg = sb * BSLACK;
            int sm = sbcur[sb] - sbeg;
            for (int i = tid; i < sm; i += 256)
                atomicAdd(&ldeg[h * 64 + (int)sbytes[sbeg + i]], 1);
        }
    }

    int lane = tid & 63;
    int og = __builtin_amdgcn_readfirstlane(tid >> 6);
    const float* wp1 = w1 + og * 16 * 64;
    const float* wp2 = w2 + og * 16 * 64;

    float a1[2][16], a2[2][16];
#pragma unroll
    for (int o = 0; o < 16; o++) {
        float bb1 = b1[og * 16 + o], bb2 = b2[og * 16 + o];
        a1[0][o] = bb1; a1[1][o] = bb1;
        a2[0][o] = bb2; a2[1][o] = bb2;
    }

    for (int fq = 0; fq < 16; fq++) {
        float4 fv0 = *(const float4*)&sf[lane * 68 + fq * 4];
        float4 fv1 = *(const float4*)&sf[(lane + 64) * 68 + fq * 4];
#pragma unroll
        for (int o = 0; o < 16; o++) {
            float4 wv1 = *(const float4*)&wp1[o * 64 + fq * 4];
            float4 wv2 = *(const float4*)&wp2[o * 64 + fq * 4];
            a1[0][o] += fv0.x * wv1.x + fv0.y * wv1.y + fv0.z * wv1.z + fv0.w * wv1.w;
            a1[1][o] += fv1.x * wv1.x + fv1.y * wv1.y + fv1.z * wv1.z + fv1.w * wv1.w;
            a2[0][o] += fv0.x * wv2.x + fv0.y * wv2.y + fv0.z * wv2.z + fv0.w * wv2.w;
            a2[1][o] += fv1.x * wv2.x + fv1.y * wv2.y + fv1.z * wv2.z + fv1.w * wv2.w;
        }
    }

    __syncthreads();   // ldeg complete before epilogue reads it

#pragma unroll
    for (int j = 0; j < 2; j++) {
        int g = base + lane + j * 64;
        if (g >= N_NODESC) continue;
        float is = rsqrtf(fmaxf((float)ldeg[j * 64 + lane], 1.f));
#pragma unroll
        for (int oq = 0; oq < 4; oq++) {
            float4 t, u;
            t.x = fast_tanh(a1[j][oq * 4 + 0]); t.y = fast_tanh(a1[j][oq * 4 + 1]);
            t.z = fast_tanh(a1[j][oq * 4 + 2]); t.w = fast_tanh(a1[j][oq * 4 + 3]);
            u.x = a2[j][oq * 4 + 0] * is;   u.y = a2[j][oq * 4 + 1] * is;
            u.z = a2[j][oq * 4 + 2] * is;   u.w = a2[j][oq * 4 + 3] * is;
            ((float4*)h1)[(size_t)g * 16 + og * 4 + oq] = t;
            ((float4*)xs)[(size_t)g * 16 + og * 4 + oq] = u;
        }
    }
}

// ---------------- per-bucket: LDS node-sort, then wave-per-node register accumulation ----------------
// fp32 scalar gather: uniform __shfl -> readlane -> SGPR base + lane offset.
// PERMANENTLY CLOSED: bytes-bound at ~6.3 TB/s delivered (r14 A/B); every
// fp16/pairing variant regressed 1.75-1.85x (r10/r11/r17).
__global__ __launch_bounds__(256) void agg4_kernel(const int* __restrict__ bcur,
                                                   const unsigned* __restrict__ bedges,
                                                   const float* __restrict__ xs,
                                                   float* __restrict__ h2) {
    __shared__ unsigned eraw[BSLACK];
    __shared__ unsigned eled[BSLACK];
    __shared__ int loff[65];
    __shared__ int lcnt[64];
    __shared__ int lcur[64];
    int tid = threadIdx.x, lane = tid & 63, wid = tid >> 6;
    int b = blockIdx.x;
    int beg = b * BSLACK;
    int m = bcur[b] - beg;             // edges in this bucket

    if (tid < 64) lcnt[tid] = 0;
    __syncthreads();
    for (int i = tid; i < m; i += 256) {
        unsigned pk = bedges[beg + i];
        eraw[i] = pk;
        atomicAdd(&lcnt[pk >> 17], 1);
    }
    __syncthreads();
    if (wid == 0) {                    // 64-entry exclusive scan in wave 0
        int c = lcnt[lane];
        int v = c;
#pragma unroll
        for (int off = 1; off < 64; off <<= 1) {
            int t = __shfl_up(v, off, 64);
            if (lane >= off) v += t;
        }
        loff[lane] = v - c;
        lcur[lane] = v - c;
        if (lane == 63) loff[64] = v;  // == m
    }
    __syncthreads();
    for (int i = tid; i < m; i += 256) {
        unsigned pk = eraw[i];
        int pos = atomicAdd(&lcur[pk >> 17], 1);
        eled[pos] = pk & 0x1FFFFu;
    }
    __syncthreads();

    int nbase = b * 64;
#pragma unroll 1
    for (int t = 0; t < 16; t++) {
        int nl = wid * 16 + t;
        int s0 = loff[nl], s1 = loff[nl + 1];
        float acc = 0.f;
        for (int k = s0; k < s1; k += 16) {
            int cnt = s1 - k; if (cnt > 16) cnt = 16;   // wave-uniform
            unsigned sv = eled[min(k + (lane & 15), s1 - 1)];
            float v[16];
#pragma unroll
            for (int j = 0; j < 16; j++) {
                if (j < cnt) {
                    int sj = __shfl((int)sv, j, 64);
                    v[j] = xs[(size_t)sj * 64 + lane];
                }
            }
#pragma unroll
            for (int j = 0; j < 16; j++)
                if (j < cnt) acc += v[j];
        }
        int g = nbase + nl;
        if (g < N_NODESC) {
            float isq = rsqrtf(fmaxf((float)(s1 - s0), 1.f));
            h2[(size_t)g * 64 + lane] = acc * isq;
        }
    }
}

// ---------------- channel-attention scores (r16-proven) + spread atomics ----------------
// Change vs r16: wsum accumulation spread over 32 slots/branch
// (blockIdx&31) -- 1563 same-address RMWs per branch was a ~20us serial
// chain candidate (same poison as r2/r6). out_kernel sums the 64 scalars.
__global__ __launch_bounds__(256) void att3_kernel(const float* __restrict__ h1,
                                                   const float* __restrict__ h2,
                                                   const float* __restrict__ aw1,
                                                   const float* __restrict__ ab1,
                                                   const float* __restrict__ aw2,
                                                   float* __restrict__ wsum) {
    __shared__ float sf[2][64 * 68];
    __shared__ float ssc[2][2][64];    // [branch][cgroup][node]
    int tid = threadIdx.x, lane = tid & 63;
    int wid = __builtin_amdgcn_readfirstlane(tid >> 6);
    int br = wid >> 1, cg = wid & 1;   // wave-uniform scalars
    int base = blockIdx.x * 64;

    // stage both branches: 4 f4/thread/branch, all 8 issued before barrier
#pragma unroll
    for (int b = 0; b < 2; b++) {
        const float* H = b ? h2 : h1;
#pragma unroll
        for (int k = 0; k < 4; k++) {
            int fi = tid + k * 256;
            int node = fi >> 4, f4 = fi & 15;
            float4 v = make_float4(0.f, 0.f, 0.f, 0.f);
            if (base + node < N_NODESC)
                v = ((const float4*)H)[(size_t)(base + node) * 16 + f4];
            float* d = &sf[b][node * 68 + f4 * 4];
            d[0] = v.x; d[1] = v.y; d[2] = v.z; d[3] = v.w;
        }
    }
    __syncthreads();

    // wave (br,cg): lane <-> node, channels cg*16..cg*16+15
    float acc[16];
#pragma unroll
    for (int c = 0; c < 16; c++) acc[c] = ab1[cg * 16 + c];
    const float* sfb = &sf[br][lane * 68];
    for (int fq = 0; fq < 16; fq++) {
        float4 hv = *(const float4*)&sfb[fq * 4];
#pragma unroll
        for (int k = 0; k < 4; k++) {
            float h = (k == 0) ? hv.x : (k == 1) ? hv.y : (k == 2) ? hv.z : hv.w;
            const float* wp = &aw1[(fq * 4 + k) * 32 + cg * 16];  // uniform addr
#pragma unroll
            for (int cq = 0; cq < 4; cq++) {
                float4 wv = *(const float4*)&wp[cq * 4];
                acc[cq * 4 + 0] += h * wv.x; acc[cq * 4 + 1] += h * wv.y;
                acc[cq * 4 + 2] += h * wv.z; acc[cq * 4 + 3] += h * wv.w;
            }
        }
    }
    float s = 0.f;
#pragma unroll
    for (int c = 0; c < 16; c++) s += fast_tanh(acc[c]) * aw2[cg * 16 + c];
    ssc[br][cg][lane] = s;
    __syncthreads();

    // reduce: threads 0..127 cover [branch][node]; branch uniform per wave
    if (tid < 128) {
        int b2 = tid >> 6, node = tid & 63;
        float v = ssc[b2][0][node] + ssc[b2][1][node];
        if (base + node >= N_NODESC) v = 0.f;
#pragma unroll
        for (int off = 32; off; off >>= 1) v += __shfl_down(v, off, 64);
        if (node == 0)
            atomicAdd(&wsum[b2 * NSLOT + (blockIdx.x & (NSLOT - 1))], v);
    }
}

// ---------------- fused beta + combine + fc2 (sums the 64 wsum slots) ----------------
__global__ __launch_bounds__(256) void out_kernel(const float* __restrict__ h1,
                                                  const float* __restrict__ h2,
                                                  const float* __restrict__ wsum,
                                                  const float* __restrict__ w,
                                                  const float* __restrict__ b,
                                                  float* __restrict__ out) {
    __shared__ float sw[16 * 68];
    int tid = threadIdx.x;
    {
        int o = tid >> 4, f4 = tid & 15;
        float4 v = ((const float4*)w)[tid];
        float* d = &sw[o * 68 + f4 * 4];
        d[0] = v.x; d[1] = v.y; d[2] = v.z; d[3] = v.w;
    }
    __syncthreads();
    float w0 = 0.f, w1 = 0.f;
#pragma unroll
    for (int i = 0; i < NSLOT; i++) {          // uniform-address s_loads, L2-hot
        w0 += wsum[i];
        w1 += wsum[NSLOT + i];
    }
    w0 *= (1.f / (float)N_NODESC);
    w1 *= (1.f / (float)N_NODESC);
    float mx = fmaxf(w0, w1);
    float e0 = __expf(w0 - mx), e1 = __expf(w1 - mx);
    float inv = 1.f / (e0 + e1);
    float b0 = e0 * inv, b1v = e1 * inv;

    int o = tid & 15, ln = tid >> 4;
    int node = blockIdx.x * 16 + ln;
    if (node >= N_NODESC) return;
    const float4* r1 = (const float4*)(h1 + (size_t)node * 64);
    const float4* r2 = (const float4*)(h2 + (size_t)node * 64);
    float acc = b[o];
    for (int fq = 0; fq < 16; fq++) {
        float4 x1 = r1[fq], x2 = r2[fq];
        float4 wv = *(const float4*)&sw[o * 68 + fq * 4];
        acc += (b0 * x1.x + b1v * x2.x) * wv.x + (b0 * x1.y + b1v * x2.y) * wv.y
             + (b0 * x1.z + b1v * x2.z) * wv.z + (b0 * x1.w + b1v * x2.w) * wv.w;
    }
    out[(size_t)node * 16 + o] = acc;
}

extern "C" void kernel_launch(void* const* d_in, const int* in_sizes, int n_in,
                              void* d_out, int out_size, void* d_ws, size_t ws_size,
                              hipStream_t stream) {
    (void)in_sizes; (void)n_in; (void)out_size; (void)ws_size;
    const float* feat = (const float*)d_in[0];
    const int*   esrc = (const int*)d_in[1];
    const int*   edst = (const int*)d_in[2];
    const float* fc1w = (const float*)d_in[3];
    const float* fc1b = (const float*)d_in[4];
    const float* fltw = (const float*)d_in[5];
    const float* fltb = (const float*)d_in[6];
    const float* aw1  = (const float*)d_in[7];
    const float* ab1  = (const float*)d_in[8];
    const float* aw2  = (const float*)d_in[9];
    const float* fc2w = (const float*)d_in[10];
    const float* fc2b = (const float*)d_in[11];
    float* out = (float*)d_out;

    char* ws = (char*)d_ws;
    size_t off = 0;
    auto alloc = [&](size_t bytes) {
        char* p = ws + off;
        off += (bytes + 255) & ~(size_t)255;
        return p;
    };
    float*         h1     = (float*)alloc((size_t)N_NODESC * 64 * 4);
    float*         xs     = (float*)alloc((size_t)N_NODESC * 64 * 4);
    float*         h2     = (float*)alloc((size_t)N_NODESC * 64 * 4);
    int*           bcur   = (int*)alloc((size_t)NBUCK * 4);
    int*           sbcur  = (int*)alloc((size_t)NBUCK * 4);
    unsigned*      bedges = (unsigned*)alloc((size_t)NBUCK * BSLACK * 4);  // 8 MB
    unsigned char* sbytes = (unsigned char*)alloc((size_t)NBUCK * BSLACK); // 2 MB
    float*         wsum   = (float*)alloc(2 * NSLOT * 4);

    hipMemsetAsync(wsum, 0, 2 * NSLOT * 4, stream);

    binit_kernel<<<(NBUCK + 255) / 256, 256, 0, stream>>>(bcur, sbcur);
    scatter_dual_kernel<<<NSBLK, 1024, 0, stream>>>(esrc, edst, bcur, sbcur,
                                                    bedges, sbytes);
    gemm_kernel<<<(N_NODESC + 127) / 128, 256, 0, stream>>>(
        feat, fc1w, fc1b, fltw, fltb, sbcur, sbytes, h1, xs);
    agg4_kernel<<<NBUCK, 256, 0, stream>>>(bcur, bedges, xs, h2);
    att3_kernel<<<NBUCK, 256, 0, stream>>>(h1, h2, aw1, ab1, aw2, wsum);
    out_kernel<<<(N_NODESC + 15) / 16, 256, 0, stream>>>(h1, h2, wsum,
                                                         fc2w, fc2b, out);
}

// Round 19
// 290.655 us; speedup vs baseline: 1.2987x; 1.0264x over previous
//
#include <hip/hip_runtime.h>
#include <math.h>

#define N_NODESC 100000
#define N_EDGESC 1600000
#define NBUCK 1563        // ceil(100000 / 64) -- 64 nodes per bucket (both sorts)
#define BSLACK 1280       // slots per bucket region (mean 1024 + 8 sigma)
#define SCHUNK 8192       // edges per scatter block -> 196 blocks (halves mid-phase RMW chains)
#define NSBLK 196         // ceil(1.6M / 8192)
#define NSLOT 32          // wsum accumulation slots per branch (atomic spread)

// fast tanh via native exp: tanh(x) = sign(x) * (1 - e) / (1 + e), e = exp(-2|x|)
__device__ __forceinline__ float fast_tanh(float x) {
    float ax = fabsf(x);
    float e = __expf(-2.f * ax);
    float r = (1.f - e) * __builtin_amdgcn_rcpf(1.f + e);
    return copysignf(r, x);
}

// ---------------- dual counting sort: dst-sort (edges) + src-sort (1-byte ids) ----------------
// bcur0/sbcur0 are zero-initialized counters (binit dispatch eliminated);
// absolute slot base = bucket*BSLACK + running count.
__global__ __launch_bounds__(1024) void scatter_dual_kernel(
    const int* __restrict__ src, const int* __restrict__ dst,
    int* __restrict__ bcur0, int* __restrict__ sbcur0,
    unsigned* __restrict__ bedges, unsigned char* __restrict__ sbytes) {
    __shared__ int histd[NBUCK];
    __shared__ int hists[NBUCK];
    int tid = threadIdx.x;
    int e_beg = blockIdx.x * SCHUNK;
    int e_end = min(e_beg + SCHUNK, N_EDGESC);
    for (int i = tid; i < NBUCK; i += 1024) { histd[i] = 0; hists[i] = 0; }
    __syncthreads();

    int ss[8], dd[8];
    int cnt = 0;
    for (int i = e_beg + tid; i < e_end; i += 1024) {
        ss[cnt] = src[i];
        dd[cnt] = dst[i];
        cnt++;
    }
#pragma unroll
    for (int j = 0; j < 8; j++) {
        if (j < cnt) {
            atomicAdd(&histd[dd[j] >> 6], 1);
            atomicAdd(&hists[ss[j] >> 6], 1);
        }
    }
    __syncthreads();
    for (int i = tid; i < NBUCK; i += 1024) {
        int c = histd[i];
        if (c > 0) histd[i] = i * BSLACK + atomicAdd(&bcur0[i], c);
        int c2 = hists[i];
        if (c2 > 0) hists[i] = i * BSLACK + atomicAdd(&sbcur0[i], c2);
    }
    __syncthreads();
#pragma unroll
    for (int j = 0; j < 8; j++) {
        if (j < cnt) {
            int slot = atomicAdd(&histd[dd[j] >> 6], 1);
            bedges[slot] = (unsigned)ss[j] | ((unsigned)(dd[j] & 63) << 17);
            int slot2 = atomicAdd(&hists[ss[j] >> 6], 1);
            sbytes[slot2] = (unsigned char)(ss[j] & 63);
        }
    }
}

// ---------------- fused fc1 (tanh) + filt GEMM; deg rebuilt from src-sort ----------------
// xs fp32 (fp16 gather refuted three ways: r10 sub-dword, r11 bpermute,
// r17 conditional-voffset -- all ~115-120us vs 64.5us fp32).
__global__ __launch_bounds__(256) void gemm_kernel(
    const float* __restrict__ feat,
    const float* __restrict__ w1, const float* __restrict__ b1,
    const float* __restrict__ w2, const float* __restrict__ b2,
    const int* __restrict__ sbcur0, const unsigned char* __restrict__ sbytes,
    float* __restrict__ h1, float* __restrict__ xs) {
    __shared__ float sf[128 * 68];
    __shared__ int ldeg[128];
    int tid = threadIdx.x;
    int base = blockIdx.x * 128;
    if (tid < 128) ldeg[tid] = 0;
    for (int k = 0; k < 8; k++) {
        int fi = tid + k * 256;
        int node = fi >> 4, f4 = fi & 15;
        float4 v = make_float4(0.f, 0.f, 0.f, 0.f);
        if (base + node < N_NODESC)
            v = ((const float4*)feat)[(size_t)(base + node) * 16 + f4];
        float* d = &sf[node * 68 + f4 * 4];
        d[0] = v.x; d[1] = v.y; d[2] = v.z; d[3] = v.w;
    }
    __syncthreads();

    // out-degree count for this block's 128 nodes (2 src-buckets)
#pragma unroll
    for (int h = 0; h < 2; h++) {
        int sb = blockIdx.x * 2 + h;
        if (sb < NBUCK) {
            int sbeg = sb * BSLACK;
            int sm = sbcur0[sb];
            for (int i = tid; i < sm; i += 256)
                atomicAdd(&ldeg[h * 64 + (int)sbytes[sbeg + i]], 1);
        }
    }

    int lane = tid & 63;
    int og = __builtin_amdgcn_readfirstlane(tid >> 6);
    const float* wp1 = w1 + og * 16 * 64;
    const float* wp2 = w2 + og * 16 * 64;

    float a1[2][16], a2[2][16];
#pragma unroll
    for (int o = 0; o < 16; o++) {
        float bb1 = b1[og * 16 + o], bb2 = b2[og * 16 + o];
        a1[0][o] = bb1; a1[1][o] = bb1;
        a2[0][o] = bb2; a2[1][o] = bb2;
    }

    for (int fq = 0; fq < 16; fq++) {
        float4 fv0 = *(const float4*)&sf[lane * 68 + fq * 4];
        float4 fv1 = *(const float4*)&sf[(lane + 64) * 68 + fq * 4];
#pragma unroll
        for (int o = 0; o < 16; o++) {
            float4 wv1 = *(const float4*)&wp1[o * 64 + fq * 4];
            float4 wv2 = *(const float4*)&wp2[o * 64 + fq * 4];
            a1[0][o] += fv0.x * wv1.x + fv0.y * wv1.y + fv0.z * wv1.z + fv0.w * wv1.w;
            a1[1][o] += fv1.x * wv1.x + fv1.y * wv1.y + fv1.z * wv1.z + fv1.w * wv1.w;
            a2[0][o] += fv0.x * wv2.x + fv0.y * wv2.y + fv0.z * wv2.z + fv0.w * wv2.w;
            a2[1][o] += fv1.x * wv2.x + fv1.y * wv2.y + fv1.z * wv2.z + fv1.w * wv2.w;
        }
    }

    __syncthreads();   // ldeg complete before epilogue reads it

#pragma unroll
    for (int j = 0; j < 2; j++) {
        int g = base + lane + j * 64;
        if (g >= N_NODESC) continue;
        float is = rsqrtf(fmaxf((float)ldeg[j * 64 + lane], 1.f));
#pragma unroll
        for (int oq = 0; oq < 4; oq++) {
            float4 t, u;
            t.x = fast_tanh(a1[j][oq * 4 + 0]); t.y = fast_tanh(a1[j][oq * 4 + 1]);
            t.z = fast_tanh(a1[j][oq * 4 + 2]); t.w = fast_tanh(a1[j][oq * 4 + 3]);
            u.x = a2[j][oq * 4 + 0] * is;   u.y = a2[j][oq * 4 + 1] * is;
            u.z = a2[j][oq * 4 + 2] * is;   u.w = a2[j][oq * 4 + 3] * is;
            ((float4*)h1)[(size_t)g * 16 + og * 4 + oq] = t;
            ((float4*)xs)[(size_t)g * 16 + og * 4 + oq] = u;
        }
    }
}

// ---------------- per-bucket: LDS node-sort, then wave-per-node register accumulation ----------------
// fp32 scalar gather: uniform __shfl -> readlane -> SGPR base + lane offset.
// PERMANENTLY CLOSED: bytes-bound at ~6.3 TB/s delivered (r14 A/B).
__global__ __launch_bounds__(256) void agg4_kernel(const int* __restrict__ bcur0,
                                                   const unsigned* __restrict__ bedges,
                                                   const float* __restrict__ xs,
                                                   float* __restrict__ h2) {
    __shared__ unsigned eraw[BSLACK];
    __shared__ unsigned eled[BSLACK];
    __shared__ int loff[65];
    __shared__ int lcnt[64];
    __shared__ int lcur[64];
    int tid = threadIdx.x, lane = tid & 63, wid = tid >> 6;
    int b = blockIdx.x;
    int beg = b * BSLACK;
    int m = bcur0[b];                  // edges in this bucket (count-only now)

    if (tid < 64) lcnt[tid] = 0;
    __syncthreads();
    for (int i = tid; i < m; i += 256) {
        unsigned pk = bedges[beg + i];
        eraw[i] = pk;
        atomicAdd(&lcnt[pk >> 17], 1);
    }
    __syncthreads();
    if (wid == 0) {                    // 64-entry exclusive scan in wave 0
        int c = lcnt[lane];
        int v = c;
#pragma unroll
        for (int off = 1; off < 64; off <<= 1) {
            int t = __shfl_up(v, off, 64);
            if (lane >= off) v += t;
        }
        loff[lane] = v - c;
        lcur[lane] = v - c;
        if (lane == 63) loff[64] = v;  // == m
    }
    __syncthreads();
    for (int i = tid; i < m; i += 256) {
        unsigned pk = eraw[i];
        int pos = atomicAdd(&lcur[pk >> 17], 1);
        eled[pos] = pk & 0x1FFFFu;
    }
    __syncthreads();

    int nbase = b * 64;
#pragma unroll 1
    for (int t = 0; t < 16; t++) {
        int nl = wid * 16 + t;
        int s0 = loff[nl], s1 = loff[nl + 1];
        float acc = 0.f;
        for (int k = s0; k < s1; k += 16) {
            int cnt = s1 - k; if (cnt > 16) cnt = 16;   // wave-uniform
            unsigned sv = eled[min(k + (lane & 15), s1 - 1)];
            float v[16];
#pragma unroll
            for (int j = 0; j < 16; j++) {
                if (j < cnt) {
                    int sj = __shfl((int)sv, j, 64);
                    v[j] = xs[(size_t)sj * 64 + lane];
                }
            }
#pragma unroll
            for (int j = 0; j < 16; j++)
                if (j < cnt) acc += v[j];
        }
        int g = nbase + nl;
        if (g < N_NODESC) {
            float isq = rsqrtf(fmaxf((float)(s1 - s0), 1.f));
            h2[(size_t)g * 64 + lane] = acc * isq;
        }
    }
}

// ---------------- channel-attention scores (r16-proven) + spread atomics (r18-proven) ----------------
__global__ __launch_bounds__(256) void att3_kernel(const float* __restrict__ h1,
                                                   const float* __restrict__ h2,
                                                   const float* __restrict__ aw1,
                                                   const float* __restrict__ ab1,
                                                   const float* __restrict__ aw2,
                                                   float* __restrict__ wsum) {
    __shared__ float sf[2][64 * 68];
    __shared__ float ssc[2][2][64];    // [branch][cgroup][node]
    int tid = threadIdx.x, lane = tid & 63;
    int wid = __builtin_amdgcn_readfirstlane(tid >> 6);
    int br = wid >> 1, cg = wid & 1;   // wave-uniform scalars
    int base = blockIdx.x * 64;

    // stage both branches: 4 f4/thread/branch, all 8 issued before barrier
#pragma unroll
    for (int b = 0; b < 2; b++) {
        const float* H = b ? h2 : h1;
#pragma unroll
        for (int k = 0; k < 4; k++) {
            int fi = tid + k * 256;
            int node = fi >> 4, f4 = fi & 15;
            float4 v = make_float4(0.f, 0.f, 0.f, 0.f);
            if (base + node < N_NODESC)
                v = ((const float4*)H)[(size_t)(base + node) * 16 + f4];
            float* d = &sf[b][node * 68 + f4 * 4];
            d[0] = v.x; d[1] = v.y; d[2] = v.z; d[3] = v.w;
        }
    }
    __syncthreads();

    // wave (br,cg): lane <-> node, channels cg*16..cg*16+15
    float acc[16];
#pragma unroll
    for (int c = 0; c < 16; c++) acc[c] = ab1[cg * 16 + c];
    const float* sfb = &sf[br][lane * 68];
    for (int fq = 0; fq < 16; fq++) {
        float4 hv = *(const float4*)&sfb[fq * 4];
#pragma unroll
        for (int k = 0; k < 4; k++) {
            float h = (k == 0) ? hv.x : (k == 1) ? hv.y : (k == 2) ? hv.z : hv.w;
            const float* wp = &aw1[(fq * 4 + k) * 32 + cg * 16];  // uniform addr
#pragma unroll
            for (int cq = 0; cq < 4; cq++) {
                float4 wv = *(const float4*)&wp[cq * 4];
                acc[cq * 4 + 0] += h * wv.x; acc[cq * 4 + 1] += h * wv.y;
                acc[cq * 4 + 2] += h * wv.z; acc[cq * 4 + 3] += h * wv.w;
            }
        }
    }
    float s = 0.f;
#pragma unroll
    for (int c = 0; c < 16; c++) s += fast_tanh(acc[c]) * aw2[cg * 16 + c];
    ssc[br][cg][lane] = s;
    __syncthreads();

    // reduce: threads 0..127 cover [branch][node]; branch uniform per wave
    if (tid < 128) {
        int b2 = tid >> 6, node = tid & 63;
        float v = ssc[b2][0][node] + ssc[b2][1][node];
        if (base + node >= N_NODESC) v = 0.f;
#pragma unroll
        for (int off = 32; off; off >>= 1) v += __shfl_down(v, off, 64);
        if (node == 0)
            atomicAdd(&wsum[b2 * NSLOT + (blockIdx.x & (NSLOT - 1))], v);
    }
}

// ---------------- fused beta + combine + fc2 (sums the 64 wsum slots) ----------------
__global__ __launch_bounds__(256) void out_kernel(const float* __restrict__ h1,
                                                  const float* __restrict__ h2,
                                                  const float* __restrict__ wsum,
                                                  const float* __restrict__ w,
                                                  const float* __restrict__ b,
                                                  float* __restrict__ out) {
    __shared__ float sw[16 * 68];
    int tid = threadIdx.x;
    {
        int o = tid >> 4, f4 = tid & 15;
        float4 v = ((const float4*)w)[tid];
        float* d = &sw[o * 68 + f4 * 4];
        d[0] = v.x; d[1] = v.y; d[2] = v.z; d[3] = v.w;
    }
    __syncthreads();
    float w0 = 0.f, w1 = 0.f;
#pragma unroll
    for (int i = 0; i < NSLOT; i++) {          // uniform-address s_loads, L2-hot
        w0 += wsum[i];
        w1 += wsum[NSLOT + i];
    }
    w0 *= (1.f / (float)N_NODESC);
    w1 *= (1.f / (float)N_NODESC);
    float mx = fmaxf(w0, w1);
    float e0 = __expf(w0 - mx), e1 = __expf(w1 - mx);
    float inv = 1.f / (e0 + e1);
    float b0 = e0 * inv, b1v = e1 * inv;

    int o = tid & 15, ln = tid >> 4;
    int node = blockIdx.x * 16 + ln;
    if (node >= N_NODESC) return;
    const float4* r1 = (const float4*)(h1 + (size_t)node * 64);
    const float4* r2 = (const float4*)(h2 + (size_t)node * 64);
    float acc = b[o];
    for (int fq = 0; fq < 16; fq++) {
        float4 x1 = r1[fq], x2 = r2[fq];
        float4 wv = *(const float4*)&sw[o * 68 + fq * 4];
        acc += (b0 * x1.x + b1v * x2.x) * wv.x + (b0 * x1.y + b1v * x2.y) * wv.y
             + (b0 * x1.z + b1v * x2.z) * wv.z + (b0 * x1.w + b1v * x2.w) * wv.w;
    }
    out[(size_t)node * 16 + o] = acc;
}

extern "C" void kernel_launch(void* const* d_in, const int* in_sizes, int n_in,
                              void* d_out, int out_size, void* d_ws, size_t ws_size,
                              hipStream_t stream) {
    (void)in_sizes; (void)n_in; (void)out_size; (void)ws_size;
    const float* feat = (const float*)d_in[0];
    const int*   esrc = (const int*)d_in[1];
    const int*   edst = (const int*)d_in[2];
    const float* fc1w = (const float*)d_in[3];
    const float* fc1b = (const float*)d_in[4];
    const float* fltw = (const float*)d_in[5];
    const float* fltb = (const float*)d_in[6];
    const float* aw1  = (const float*)d_in[7];
    const float* ab1  = (const float*)d_in[8];
    const float* aw2  = (const float*)d_in[9];
    const float* fc2w = (const float*)d_in[10];
    const float* fc2b = (const float*)d_in[11];
    float* out = (float*)d_out;

    char* ws = (char*)d_ws;
    size_t off = 0;
    auto alloc = [&](size_t bytes) {
        char* p = ws + off;
        off += (bytes + 255) & ~(size_t)255;
        return p;
    };
    float*         h1     = (float*)alloc((size_t)N_NODESC * 64 * 4);
    float*         xs     = (float*)alloc((size_t)N_NODESC * 64 * 4);
    float*         h2     = (float*)alloc((size_t)N_NODESC * 64 * 4);
    // zero-init counter block: bcur0[NBUCK] | sbcur0[NBUCK] | wsum[2*NSLOT]
    int*           zblk   = (int*)alloc((size_t)(2 * NBUCK + 2 * NSLOT) * 4);
    unsigned*      bedges = (unsigned*)alloc((size_t)NBUCK * BSLACK * 4);  // 8 MB
    unsigned char* sbytes = (unsigned char*)alloc((size_t)NBUCK * BSLACK); // 2 MB

    int*   bcur0  = zblk;
    int*   sbcur0 = zblk + NBUCK;
    float* wsum   = (float*)(zblk + 2 * NBUCK);

    hipMemsetAsync(zblk, 0, (size_t)(2 * NBUCK + 2 * NSLOT) * 4, stream);

    scatter_dual_kernel<<<NSBLK, 1024, 0, stream>>>(esrc, edst, bcur0, sbcur0,
                                                    bedges, sbytes);
    gemm_kernel<<<(N_NODESC + 127) / 128, 256, 0, stream>>>(
        feat, fc1w, fc1b, fltw, fltb, sbcur0, sbytes, h1, xs);
    agg4_kernel<<<NBUCK, 256, 0, stream>>>(bcur0, bedges, xs, h2);
    att3_kernel<<<NBUCK, 256, 0, stream>>>(h1, h2, aw1, ab1, aw2, wsum);
    out_kernel<<<(N_NODESC + 15) / 16, 256, 0, stream>>>(h1, h2, wsum,
                                                         fc2w, fc2b, out);
}